// Round 11
// baseline (3827.191 us; speedup 1.0000x reference)
//
#include <hip/hip_runtime.h>
#include <stdint.h>

#pragma clang fp contract(off)

#define T_STEPS 784
#define NH 64
#define NOUT 10

// v_fma_mix_f32: D.f32 = fma(cvt(S0), S1.f32, S2.f32) where S0 is read as an
// f16 half (op_sel_hi[0]=1 selects f16 type; op_sel[0] picks lo/hi half).
// f16 0.0/1.0 convert EXACTLY to f32, then a normal IEEE-rn f32 fma executes
// -> each row's ascending-k single-accumulator chain is bit-identical to the
// __fmaf_rn chain proven in rounds 3-9 (absmax 9.77e-4 vs np-f32 reference).
#define MIX_LO(acc, s, w) \
    asm("v_fma_mix_f32 %0, %1, %2, %0 op_sel:[0,0,0] op_sel_hi:[1,0,0]" \
        : "+v"(acc) : "v"(s), "v"(w))
#define MIX_HI(acc, s, w) \
    asm("v_fma_mix_f32 %0, %1, %2, %0 op_sel:[1,0,0] op_sel_hi:[1,0,0]" \
        : "+v"(acc) : "v"(s), "v"(w))

// th = (th + mem*co) - ((th-0.5)*0.02), each op rounded, old mem  (r3-verified)
#define THUP(tt, mm) { const float p_ = (mm) * co; const float q_ = (tt) + p_; \
    const float r_ = (tt) - 0.5f; const float rs_ = r_ * 0.02f; (tt) = q_ - rs_; }
// mem = (spike ? 0 : mem*0.5) + h   (r3-verified)
#define MEMUP(mm, ss, hh) { const float md_ = (mm) * 0.5f; \
    const float keep_ = (ss) ? 0.0f : md_; (mm) = keep_ + (hh); }

#define H16_ONE 0x3C00u   // f16 1.0

// Four batch rows per wave; lane = neuron j. Spikes packed as f16 {a,b|c,d}
// (8B per neuron) in LDS; one uniform-address b128 read delivers 2 k's x 4
// rows; v_fma_mix consumes the halves directly (no unpack movs, no cvt).

__global__ __attribute__((amdgpu_flat_work_group_size(64, 64)))
__attribute__((amdgpu_waves_per_eu(2)))
void tesnn_main_kernel(
    const float* __restrict__ input,
    const float* __restrict__ W1, const float* __restrict__ b1,
    const float* __restrict__ W2, const float* __restrict__ b2,
    const float* __restrict__ W3, const float* __restrict__ b3,
    const float* __restrict__ Wo, const float* __restrict__ bo,
    const float* __restrict__ ce,
    float* __restrict__ out, int N)
{
    __shared__ alignas(16) uint2 sAh[NH];   // layer-1 spikes f16 {a,b},{c,d}
    __shared__ alignas(16) uint2 sBh[NH];   // layer-2 spikes

    const int lane = threadIdx.x;
    const int n0 = blockIdx.x * 4;
    if (n0 >= N) return;
    const int na = n0;
    const int nb = (n0 + 1 < N) ? n0 + 1 : N - 1;
    const int nc = (n0 + 2 < N) ? n0 + 2 : N - 1;
    const int nd = (n0 + 3 < N) ? n0 + 3 : N - 1;

    // ---- per-lane weights (lane = neuron j) ----
    const float w1 = W1[lane];
    const float bb1 = b1[lane];
    const float bb2 = b2[lane];
    const float bb3 = b3[lane];

    float w2r[NH], w3r[NH];     // row j of W2 / W3 as scalars
#pragma unroll
    for (int q = 0; q < 16; ++q) {
        float4 a = ((const float4*)W2)[lane * 16 + q];
        w2r[4 * q + 0] = a.x; w2r[4 * q + 1] = a.y;
        w2r[4 * q + 2] = a.z; w2r[4 * q + 3] = a.w;
        float4 b = ((const float4*)W3)[lane * 16 + q];
        w3r[4 * q + 0] = b.x; w3r[4 * q + 1] = b.y;
        w3r[4 * q + 2] = b.z; w3r[4 * q + 3] = b.w;
    }

    // ---- state (scalar per row: a,b,c,d) ----
    float m1a = 0.0f, t1a = 0.5f; bool s1a = false;
    float m1b = 0.0f, t1b = 0.5f; bool s1b = false;
    float m1c = 0.0f, t1c = 0.5f; bool s1c = false;
    float m1d = 0.0f, t1d = 0.5f; bool s1d = false;
    float m2a = 0.0f, t2a = 0.5f; bool s2a = false;
    float m2b = 0.0f, t2b = 0.5f; bool s2b = false;
    float m2c = 0.0f, t2c = 0.5f; bool s2c = false;
    float m2d = 0.0f, t2d = 0.5f; bool s2d = false;
    float m3a = 0.0f, t3a = 0.5f; bool s3a = false;
    float m3b = 0.0f, t3b = 0.5f; bool s3b = false;
    float m3c = 0.0f, t3c = 0.5f; bool s3c = false;
    float m3d = 0.0f, t3d = 0.5f; bool s3d = false;
    float c3fa = 0.0f, c3fb = 0.0f, c3fc = 0.0f, c3fd = 0.0f;

    const float* xra = input + (size_t)na * T_STEPS;
    const float* xrb = input + (size_t)nb * T_STEPS;
    const float* xrc = input + (size_t)nc * T_STEPS;
    const float* xrd = input + (size_t)nd * T_STEPS;
    const float* cerow = ce + (size_t)lane * T_STEPS;    // ce is [H][T]

    float xa_cur = xra[0], xb_cur = xrb[0], xc_cur = xrc[0], xd_cur = xrd[0];
    float co_cur = cerow[0];

#pragma unroll 1
    for (int t = 0; t < T_STEPS; ++t) {
        const int tn = (t < T_STEPS - 1) ? (t + 1) : (T_STEPS - 1);
        const float xa_nxt = xra[tn];
        const float xb_nxt = xrb[tn];
        const float xc_nxt = xrc[tn];
        const float xd_nxt = xrd[tn];
        const float co_nxt = cerow[tn];

        const float xa = xa_cur, xb = xb_cur, xc = xc_cur, xd = xd_cur;
        const float co = co_cur;

        // ================= layer 1 =================
        THUP(t1a, m1a) THUP(t1b, m1b) THUP(t1c, m1c) THUP(t1d, m1d)
        {
            const float ha = (xa * w1) + bb1; MEMUP(m1a, s1a, ha)
            const float hb = (xb * w1) + bb1; MEMUP(m1b, s1b, hb)
            const float hc = (xc * w1) + bb1; MEMUP(m1c, s1c, hc)
            const float hd = (xd * w1) + bb1; MEMUP(m1d, s1d, hd)
        }
        const bool p1a = m1a > t1a; s1a = p1a;
        const bool p1b = m1b > t1b; s1b = p1b;
        const bool p1c = m1c > t1c; s1c = p1c;
        const bool p1d = m1d > t1d; s1d = p1d;
        {
            const uint32_t ab = (p1a ? H16_ONE : 0u) | (p1b ? (H16_ONE << 16) : 0u);
            const uint32_t cd = (p1c ? H16_ONE : 0u) | (p1d ? (H16_ONE << 16) : 0u);
            sAh[lane] = make_uint2(ab, cd);              // ds_write_b64
        }

        // ================= layer 2 =================
        THUP(t2a, m2a) THUP(t2b, m2b) THUP(t2c, m2c) THUP(t2d, m2d)
        {
            float acc_a = 0.0f, acc_b = 0.0f, acc_c = 0.0f, acc_d = 0.0f;
            const uint4* sA4 = reinterpret_cast<const uint4*>(sAh);
#pragma unroll
            for (int g = 0; g < 32; ++g) {
                const uint4 q = sA4[g];     // {ab@2g, cd@2g, ab@2g+1, cd@2g+1}
                MIX_LO(acc_a, q.x, w2r[2 * g]);
                MIX_HI(acc_b, q.x, w2r[2 * g]);
                MIX_LO(acc_c, q.y, w2r[2 * g]);
                MIX_HI(acc_d, q.y, w2r[2 * g]);
                MIX_LO(acc_a, q.z, w2r[2 * g + 1]);
                MIX_HI(acc_b, q.z, w2r[2 * g + 1]);
                MIX_LO(acc_c, q.w, w2r[2 * g + 1]);
                MIX_HI(acc_d, q.w, w2r[2 * g + 1]);
            }
            const float h2a = acc_a + bb2; MEMUP(m2a, s2a, h2a)
            const float h2b = acc_b + bb2; MEMUP(m2b, s2b, h2b)
            const float h2c = acc_c + bb2; MEMUP(m2c, s2c, h2c)
            const float h2d = acc_d + bb2; MEMUP(m2d, s2d, h2d)
        }
        const bool p2a = m2a > t2a; s2a = p2a;
        const bool p2b = m2b > t2b; s2b = p2b;
        const bool p2c = m2c > t2c; s2c = p2c;
        const bool p2d = m2d > t2d; s2d = p2d;
        {
            const uint32_t ab = (p2a ? H16_ONE : 0u) | (p2b ? (H16_ONE << 16) : 0u);
            const uint32_t cd = (p2c ? H16_ONE : 0u) | (p2d ? (H16_ONE << 16) : 0u);
            sBh[lane] = make_uint2(ab, cd);
        }

        // ================= layer 3 =================
        THUP(t3a, m3a) THUP(t3b, m3b) THUP(t3c, m3c) THUP(t3d, m3d)
        {
            float acc_a = 0.0f, acc_b = 0.0f, acc_c = 0.0f, acc_d = 0.0f;
            const uint4* sB4 = reinterpret_cast<const uint4*>(sBh);
#pragma unroll
            for (int g = 0; g < 32; ++g) {
                const uint4 q = sB4[g];
                MIX_LO(acc_a, q.x, w3r[2 * g]);
                MIX_HI(acc_b, q.x, w3r[2 * g]);
                MIX_LO(acc_c, q.y, w3r[2 * g]);
                MIX_HI(acc_d, q.y, w3r[2 * g]);
                MIX_LO(acc_a, q.z, w3r[2 * g + 1]);
                MIX_HI(acc_b, q.z, w3r[2 * g + 1]);
                MIX_LO(acc_c, q.w, w3r[2 * g + 1]);
                MIX_HI(acc_d, q.w, w3r[2 * g + 1]);
            }
            const float h3a = acc_a + bb3; MEMUP(m3a, s3a, h3a)
            const float h3b = acc_b + bb3; MEMUP(m3b, s3b, h3b)
            const float h3c = acc_c + bb3; MEMUP(m3c, s3c, h3c)
            const float h3d = acc_d + bb3; MEMUP(m3d, s3d, h3d)
        }
        const bool p3a = m3a > t3a; s3a = p3a;
        const bool p3b = m3b > t3b; s3b = p3b;
        const bool p3c = m3c > t3c; s3c = p3c;
        const bool p3d = m3d > t3d; s3d = p3d;
        c3fa += p3a ? 1.0f : 0.0f;
        c3fb += p3b ? 1.0f : 0.0f;
        c3fc += p3c ? 1.0f : 0.0f;
        c3fd += p3d ? 1.0f : 0.0f;

        xa_cur = xa_nxt; xb_cur = xb_nxt; xc_cur = xc_nxt; xd_cur = xd_nxt;
        co_cur = co_nxt;
    }

    // ---- epilogue: out[n][o] = (sum_t s3) @ Wo.T / T + bo ----
    const double cA = (double)c3fa, cB = (double)c3fb;
    const double cC = (double)c3fc, cD = (double)c3fd;
    double rA = 0.0, rB = 0.0, rC = 0.0, rD = 0.0;
#pragma unroll
    for (int o = 0; o < NOUT; ++o) {
        const double wo = (double)Wo[o * NH + lane];
        double vA = cA * wo, vB = cB * wo, vC = cC * wo, vD = cD * wo;
#pragma unroll
        for (int off = 32; off; off >>= 1) {
            vA += __shfl_xor(vA, off, 64);
            vB += __shfl_xor(vB, off, 64);
            vC += __shfl_xor(vC, off, 64);
            vD += __shfl_xor(vD, off, 64);
        }
        if (lane == o) { rA = vA; rB = vB; rC = vC; rD = vD; }
    }
    if (lane < NOUT) {
        const double bod = (double)bo[lane];
        out[(size_t)na * NOUT + lane] = (float)(rA / (double)T_STEPS + bod);
        if (n0 + 1 < N) out[(size_t)nb * NOUT + lane] = (float)(rB / (double)T_STEPS + bod);
        if (n0 + 2 < N) out[(size_t)nc * NOUT + lane] = (float)(rC / (double)T_STEPS + bod);
        if (n0 + 3 < N) out[(size_t)nd * NOUT + lane] = (float)(rD / (double)T_STEPS + bod);
    }
}

extern "C" void kernel_launch(void* const* d_in, const int* in_sizes, int n_in,
                              void* d_out, int out_size, void* d_ws, size_t ws_size,
                              hipStream_t stream) {
    const float* input = (const float*)d_in[0];
    const float* W1 = (const float*)d_in[1];
    const float* b1 = (const float*)d_in[2];
    const float* W2 = (const float*)d_in[3];
    const float* b2 = (const float*)d_in[4];
    const float* W3 = (const float*)d_in[5];
    const float* b3 = (const float*)d_in[6];
    const float* Wo = (const float*)d_in[7];
    const float* bo = (const float*)d_in[8];
    const float* ce = (const float*)d_in[9];
    float* out = (float*)d_out;

    const int N = in_sizes[0] / T_STEPS;

    hipLaunchKernelGGL(tesnn_main_kernel,
                       dim3((N + 3) / 4), dim3(64), 0, stream,
                       input, W1, b1, W2, b2, W3, b3, Wo, bo, ce, out, N);
}